// Round 1
// 598.920 us; speedup vs baseline: 1.2771x; 1.2771x over previous
//
#include <hip/hip_runtime.h>
#include <hip/hip_bf16.h>

typedef __hip_bfloat16 bf16;
typedef unsigned short u16;
typedef unsigned int   u32;

constexpr int Hn=64, Wn=64, Cm=96, Ln=4096, Di=192, Kn=4, Ns=16, Rr=6;
constexpr int Gc=32, CH=128;   // 32 chunks of 128 positions

typedef __attribute__((ext_vector_type(8))) short bf16x8;
typedef __attribute__((ext_vector_type(4))) float f32x4;

static __device__ __forceinline__ float ldv(const float* p, long i){ return p[i]; }
static __device__ __forceinline__ float ldv(const bf16*  p, long i){ return __bfloat162float(p[i]); }
static __device__ __forceinline__ void  stv(float* p, long i, float v){ p[i] = v; }
static __device__ __forceinline__ void  stv(bf16*  p, long i, float v){ p[i] = __float2bfloat16(v); }
static __device__ __forceinline__ float bfr(u16 u){ return __uint_as_float((u32)u << 16); }
static __device__ __forceinline__ u16   fbr(float f){ bf16 h = __float2bfloat16(f); return *(u16*)&h; }
static __device__ __forceinline__ float4 ldv4(const float* p, long i){ return *(const float4*)(p + i); }
static __device__ __forceinline__ float4 ldv4(const bf16* p, long i){
  ushort4 u = *(const ushort4*)(p + i);
  return make_float4(bfr(u.x), bfr(u.y), bfr(u.z), bfr(u.w));
}
static __device__ __forceinline__ float splus(float x){ return (x > 15.f) ? x : log1pf(__expf(x)); }

// load 8 contiguous elems as a bf16 MFMA fragment (convert if f32)
static __device__ __forceinline__ bf16x8 ldb8(const float* p){
  float4 a = *(const float4*)p;
  float4 b = *(const float4*)(p + 4);
  bf16x8 r;
  r[0]=(short)fbr(a.x); r[1]=(short)fbr(a.y); r[2]=(short)fbr(a.z); r[3]=(short)fbr(a.w);
  r[4]=(short)fbr(b.x); r[5]=(short)fbr(b.y); r[6]=(short)fbr(b.z); r[7]=(short)fbr(b.w);
  return r;
}
static __device__ __forceinline__ bf16x8 ldb8(const bf16* p){
  return *(const bf16x8*)p;
}
// store 8 elems into LDS as bf16 (convert if f32)
static __device__ __forceinline__ void st8(u16* dst, const float* src){
  float4 a = *(const float4*)src;
  float4 b = *(const float4*)(src + 4);
  dst[0]=fbr(a.x); dst[1]=fbr(a.y); dst[2]=fbr(a.z); dst[3]=fbr(a.w);
  dst[4]=fbr(b.x); dst[5]=fbr(b.y); dst[6]=fbr(b.z); dst[7]=fbr(b.w);
}
static __device__ __forceinline__ void st8(u16* dst, const bf16* src){
  *(ushort4*)dst       = *(const ushort4*)src;
  *(ushort4*)(dst + 4) = *(const ushort4*)(src + 4);
}

// ---------------- dtype detector (f32 vs bf16) + Alog structure detector
__global__ void k_detect(const u16* x, const void* Alog, int* flag, int* flag2){
  __shared__ int cnt, cnt2;
  if (threadIdx.x == 0){ cnt = 0; cnt2 = 0; }
  __syncthreads();
  int local = 0;
  for (int i = threadIdx.x; i < 8192; i += 256){
    int e = (x[i] >> 7) & 0xFF;
    if (e != 0 && (e < 90 || e > 164)) local++;
  }
  atomicAdd(&cnt, local);
  __syncthreads();
  int f = (cnt > 400) ? 1 : 0;          // 1 => float32 inputs
  int bad = 0;
  for (int i = threadIdx.x; i < Di*Ns; i += 256){
    float v = f ? ((const float*)Alog)[i] : bfr(((const u16*)Alog)[i]);
    float ex = __logf((float)((i & 15) + 1));
    if (fabsf(v - ex) > 1e-5f) bad++;
  }
  atomicAdd(&cnt2, bad);
  __syncthreads();
  if (threadIdx.x == 0){ *flag = f; *flag2 = (cnt2 == 0) ? 1 : 0; }
}

// ---------------------------------------------------------------- in_proj GEMM (MFMA)
// M-tile = 64 rows, N = 384 full. 4 waves; wave w owns cols [96w, 96w+96).
// A: x[64][96] staged bf16 in LDS [64][104]; B: w[col][k] fragments from global.
template<typename T>
__device__ void inproj_body(const T* x, const T* w, u16* Xb, u16* Z, u16* sA, u16* sC){
  int tid = threadIdx.x;
  long p0 = (long)blockIdx.x * 64;
  // stage A (64 x 96) -> bf16
  for (int i = tid; i < 768; i += 256){           // 768 groups of 8
    int r = i / 12, c = (i % 12) * 8;
    st8(&sA[r*104 + c], x + p0*96 + (long)r*96 + c);
  }
  __syncthreads();
  int wid = tid >> 6, lane = tid & 63;
  int lr = lane & 15, lh = lane >> 4;
  int colbase = wid * 96;
  f32x4 acc[4][6] = {};
  #pragma unroll
  for (int ks = 0; ks < 3; ++ks){
    int k0 = ks*32 + lh*8;
    bf16x8 af[4];
    #pragma unroll
    for (int m = 0; m < 4; ++m)
      af[m] = *(const bf16x8*)&sA[(m*16 + lr)*104 + k0];
    #pragma unroll
    for (int n = 0; n < 6; ++n){
      bf16x8 b8 = ldb8(w + (long)(colbase + n*16 + lr)*96 + k0);
      #pragma unroll
      for (int m = 0; m < 4; ++m)
        acc[m][n] = __builtin_amdgcn_mfma_f32_16x16x32_bf16(af[m], b8, acc[m][n], 0, 0, 0);
    }
  }
  // C layout: col = lane&15, row = (lane>>4)*4 + reg  ->  stage to LDS, coalesced out
  #pragma unroll
  for (int n = 0; n < 6; ++n){
    int gc = colbase + n*16 + lr;
    #pragma unroll
    for (int m = 0; m < 4; ++m){
      #pragma unroll
      for (int r = 0; r < 4; ++r)
        sC[(m*16 + lh*4 + r)*392 + gc] = fbr(acc[m][n][r]);
    }
  }
  __syncthreads();
  for (int i = tid; i < 3072; i += 256){          // 64*384/8
    int r = i / 48, c = (i % 48) * 8;
    ushort4 v0 = *(const ushort4*)&sC[r*392 + c];
    ushort4 v1 = *(const ushort4*)&sC[r*392 + c + 4];
    u16* dst = (c < 192) ? (Xb + (p0 + r)*192 + c) : (Z + (p0 + r)*192 + (c - 192));
    *(ushort4*)dst       = v0;
    *(ushort4*)(dst + 4) = v1;
  }
}
__global__ __launch_bounds__(256) void k_inproj(const void* x, long xoff, const void* w,
                                                u16* Xb, u16* Z, const int* flag){
  __shared__ u16 sA[64*104];
  __shared__ u16 sC[64*392];
  if (*flag) inproj_body<float>((const float*)x + xoff, (const float*)w, Xb, Z, sA, sC);
  else       inproj_body<bf16 >((const bf16* )x + xoff, (const bf16* )w, Xb, Z, sA, sC);
}

// ------------------- depthwise conv3x3 + SiLU -> xcLD (L,D) and xcTLD (Lt,D)
template<typename T>
__device__ void conv_body(const u16* Xb, const T* cw, const T* cb,
                          u16* xcLD, u16* xcTLD, float* wle, u16* tl){
  float* ble = wle + Di*9;
  int b = blockIdx.x >> 6, h = blockIdx.x & 63;
  for (int i = threadIdx.x; i < Di*9; i += 256) wle[i] = ldv(cw, i);
  for (int i = threadIdx.x; i < Di;   i += 256) ble[i] = ldv(cb, i);
  __syncthreads();
  const u16* Xbb = Xb + (long)b*Ln*Di;
  u16* xa = xcLD  + (long)b*Ln*Di;
  u16* xb = xcTLD + (long)b*Ln*Di;
  for (int i = threadIdx.x; i < Di*Wn; i += 256){
    int w = i / 192, d = i % 192;
    float acc = ble[d];
    #pragma unroll
    for (int dh = -1; dh <= 1; ++dh){
      int hh = h + dh; if (hh < 0 || hh > 63) continue;
      #pragma unroll
      for (int dw = -1; dw <= 1; ++dw){
        int ww = w + dw; if (ww < 0 || ww > 63) continue;
        acc += wle[d*9 + (dh+1)*3 + (dw+1)] * bfr(Xbb[(long)(hh*64+ww)*Di + d]);
      }
    }
    float sv = acc / (1.f + __expf(-acc));
    tl[d*66 + w] = fbr(sv);
  }
  __syncthreads();
  for (int i = threadIdx.x; i < Di*Wn; i += 256){
    int w = i / 192, d = i % 192;
    u16 v = tl[d*66 + w];
    xa[(long)(h*64 + w)*Di + d] = v;
    xb[(long)(w*64 + h)*Di + d] = v;
  }
}
__global__ __launch_bounds__(256) void k_conv(const u16* Xb, const void* cw, const void* cb,
                                              u16* xcLD, u16* xcTLD, const int* flag){
  __shared__ float wle[Di*9 + Di];
  __shared__ u16 tl[Di*66];
  if (*flag) conv_body<float>(Xb, (const float*)cw, (const float*)cb, xcLD, xcTLD, wle, tl);
  else       conv_body<bf16 >(Xb, (const bf16* )cw, (const bf16* )cb, xcLD, xcTLD, wle, tl);
}

// --------------------------------------------- x_proj (MFMA): dts + packed B/C, scan order
// Per block: one 64-row tile of one source plane (s=0: LD, s=1: TLD).
// N = 80 cols (pad from 76): cols 0..37 -> k=s (t=col), 38..75 -> k=s+2 (t=col-38).
// Wave w owns row-frag w (16 rows) x 5 col-frags. K=192 -> 6 MFMA steps.
// C layout makes B/C pairing lane-local: C col == B col + 16 -> acc[f] pairs acc[f+1].
template<typename T>
__device__ void proj_body(const u16* xcLD, const u16* xcTLD, const T* xpw,
                          u16* dtsg, u32* BCg, u16* sA){
  int tid = threadIdx.x;
  int s = blockIdx.x & 1;
  long q0 = (long)(blockIdx.x >> 1) * 64;
  const u16* src = (s ? xcTLD : xcLD) + q0*192;
  for (int i = tid; i < 1536; i += 256){          // 64*192/8
    int r = i / 24, c = (i % 24) * 8;
    const u16* sp = src + (long)r*192 + c;
    *(ushort4*)&sA[r*200 + c]     = *(const ushort4*)sp;
    *(ushort4*)&sA[r*200 + c + 4] = *(const ushort4*)(sp + 4);
  }
  __syncthreads();
  int wid = tid >> 6, lane = tid & 63;
  int lr = lane & 15, lh = lane >> 4;
  f32x4 acc[5] = {};
  #pragma unroll
  for (int ks = 0; ks < 6; ++ks){
    int k0 = ks*32 + lh*8;
    bf16x8 a = *(const bf16x8*)&sA[(wid*16 + lr)*200 + k0];
    #pragma unroll
    for (int f = 0; f < 5; ++f){
      int c = f*16 + lr;
      int cw;
      if (c < 38)      cw = s*38 + c;
      else if (c < 76) cw = (s+2)*38 + (c - 38);
      else             cw = 0;                    // pad cols: harmless in-bounds load
      bf16x8 b8 = ldb8(xpw + (long)cw*192 + k0);
      acc[f] = __builtin_amdgcn_mfma_f32_16x16x32_bf16(a, b8, acc[f], 0, 0, 0);
    }
  }
  // epilogue scatter in scan order
  int row_l = wid*16 + lh*4;
  #pragma unroll
  for (int f = 0; f < 5; ++f){
    int c = f*16 + lr;
    if (c >= 76) continue;
    int k = (c < 38) ? s : s + 2;
    int t = (c < 38) ? c : c - 38;
    if (t >= 22) continue;                        // C cols written via B pairing
    #pragma unroll
    for (int r = 0; r < 4; ++r){
      long q = q0 + row_l + r;
      int b  = (int)(q >> 12);
      int ql = (int)(q & 4095);
      int l  = (k >= 2) ? (4095 - ql) : ql;
      long base = ((long)(b*4 + k))*4096 + l;
      if (t < 6){
        dtsg[base*6 + t] = fbr(acc[f][r]);
      } else {
        int n = t - 6;
        u32 v = (u32)fbr(acc[f][r]) | ((u32)fbr(acc[f+1][r]) << 16);
        BCg[base*16 + n] = v;
      }
    }
  }
}
__global__ __launch_bounds__(256) void k_proj(const u16* xcLD, const u16* xcTLD, const void* xpw,
                                              u16* dtsg, u32* BCg, const int* flag){
  __shared__ u16 sA[64*200];
  if (*flag) proj_body<float>(xcLD, xcTLD, (const float*)xpw, dtsg, BCg, sA);
  else       proj_body<bf16 >(xcLD, xcTLD, (const bf16* )xpw, dtsg, BCg, sA);
}

// softplus + decay pair: dl = softplus(xv), rr = exp(-dl) (reuses exp(xv))
static __device__ __forceinline__ void sp_decay(float xv, float& dl, float& rr){
  if (xv > 15.f){ dl = xv; rr = __expf(-xv); }
  else {
    float o = 1.f + __expf(xv);
    dl = __logf(o);
    rr = __builtin_amdgcn_rcpf(o);
  }
}

// -------------------------------- scan pass 1: lane=d, h[16]+a[16] in registers
template<typename T>
__device__ void scan1_body(const u16* xcLD, const u16* xcTLD, const u16* dtsg, const u32* BCg,
                           const T* Alog, const T* dtw, const T* dtb,
                           float* Sb, float* Qb, float* sdt, float* sB, u16* su, int fastA){
  int tid = threadIdx.x, blk = blockIdx.x;
  int g = blk & (Gc-1); int k = (blk >> 5) & 3; int b = blk >> 7;
  bool rev = k >= 2, odd = k & 1;
  int d = tid;
  const u16* src = (odd ? xcTLD : xcLD) + (long)b*Ln*Di;
  const u16* dlg = dtsg + (long)(b*Kn + k)*Ln*6;
  const u32* bcg = BCg + (long)(b*Kn + k)*Ln*16;
  float w[6], a[16], h[16];
  #pragma unroll
  for (int r = 0; r < 6; ++r) w[r] = ldv(dtw, ((long)k*Di + d)*6 + r);
  float bias = ldv(dtb, k*Di + d);
  #pragma unroll
  for (int n = 0; n < 16; ++n){ a[n] = -__expf(ldv(Alog, (long)d*16 + n)); h[n] = 0.f; }
  float S = 0.f;
  for (int t = 0; t < CH/64; ++t){
    int l0 = g*CH + t*64;
    __syncthreads();
    for (int i = tid; i < 384; i += 192){ int j = i/6, c = i - 6*j; sdt[j*8 + c] = bfr(dlg[(long)l0*6 + i]); }
    for (int i = tid; i < 1024; i += 192){ u32 v = bcg[(long)l0*16 + i]; sB[i] = bfr((u16)(v & 0xffff)); }
    for (int i = tid; i < 64*192; i += 192){
      int j = i / 192, dd = i % 192;
      int l = l0 + j; int pos = rev ? (Ln-1-l) : l;
      su[i] = src[(long)pos*Di + dd];
    }
    __syncthreads();
    if (fastA){
      for (int j = 0; j < 64; ++j){
        float xv = bias;
        #pragma unroll
        for (int r = 0; r < 6; ++r) xv += w[r]*sdt[j*8 + r];
        float dl, rr; sp_decay(xv, dl, rr);
        float du = dl * bfr(su[j*192 + d]);
        float Bv[16];
        *(float4*)&Bv[0]  = *(const float4*)&sB[j*16];
        *(float4*)&Bv[4]  = *(const float4*)&sB[j*16+4];
        *(float4*)&Bv[8]  = *(const float4*)&sB[j*16+8];
        *(float4*)&Bv[12] = *(const float4*)&sB[j*16+12];
        float p = rr;
        #pragma unroll
        for (int n = 0; n < 16; ++n){ h[n] = p*h[n] + du*Bv[n]; p *= rr; }
        S += dl;
      }
    } else {
      for (int j = 0; j < 64; ++j){
        float dl = bias;
        #pragma unroll
        for (int r = 0; r < 6; ++r) dl += w[r]*sdt[j*8 + r];
        dl = splus(dl);
        float du = dl * bfr(su[j*192 + d]);
        float Bv[16];
        *(float4*)&Bv[0]  = *(const float4*)&sB[j*16];
        *(float4*)&Bv[4]  = *(const float4*)&sB[j*16+4];
        *(float4*)&Bv[8]  = *(const float4*)&sB[j*16+8];
        *(float4*)&Bv[12] = *(const float4*)&sB[j*16+12];
        #pragma unroll
        for (int n = 0; n < 16; ++n) h[n] = __expf(dl*a[n])*h[n] + du*Bv[n];
        S += dl;
      }
    }
  }
  long ci = (long)(b*Kn + k)*Gc + g;
  Sb[ci*Di + d] = S;
  #pragma unroll
  for (int n = 0; n < 16; ++n) Qb[ci*3072 + (long)d*16 + n] = h[n];
}
__global__ __launch_bounds__(192,3) void k_scan1(const u16* xcLD, const u16* xcTLD, const u16* dtsg,
                                                 const u32* BCg, const void* Alog, const void* dtw,
                                                 const void* dtb, float* Sb, float* Qb,
                                                 const int* flag, const int* flag2){
  __shared__ float sdt[64*8];
  __shared__ float sB[64*16];
  __shared__ u16 su[64*192];
  int f2 = *flag2;
  if (*flag) scan1_body<float>(xcLD, xcTLD, dtsg, BCg, (const float*)Alog, (const float*)dtw,
                               (const float*)dtb, Sb, Qb, sdt, sB, su, f2);
  else       scan1_body<bf16 >(xcLD, xcTLD, dtsg, BCg, (const bf16* )Alog, (const bf16* )dtw,
                               (const bf16* )dtb, Sb, Qb, sdt, sB, su, f2);
}

// ---------------------- cross-chunk fixup: Hin[g] = scan of (exp(a*S), Q) over g
template<typename T>
__device__ void fix_body(const float* Sb, const float* Qb, const T* Alog, float* Hin){
  int bk = blockIdx.x;
  for (int s = threadIdx.x; s < 3072; s += 256){
    int d = s >> 4, n = s & 15;
    float a = -__expf(ldv(Alog, (long)d*16 + n));
    float h = 0.f;
    for (int g = 0; g < Gc; ++g){
      long ci = (long)bk*Gc + g;
      Hin[ci*3072 + s] = h;
      h = __expf(a * Sb[ci*Di + d]) * h + Qb[ci*3072 + s];
    }
  }
}
__global__ __launch_bounds__(256) void k_fix(const float* Sb, const float* Qb, const void* Alog,
                                             float* Hin, const int* flag){
  if (*flag) fix_body<float>(Sb, Qb, (const float*)Alog, Hin);
  else       fix_body<bf16 >(Sb, Qb, (const bf16* )Alog, Hin);
}

// -------------------------------- scan pass 2: rescan from Hin, emit ys (L,D)
template<typename T>
__device__ void scan2_body(const u16* xcLD, const u16* xcTLD, const u16* dtsg, const u32* BCg,
                           const T* Alog, const T* dtw, const T* dtb, const float* Hin,
                           u16* ys, float* sdt, float* sB, float* sC, u16* su, int fastA){
  int tid = threadIdx.x, blk = blockIdx.x;
  int g = blk & (Gc-1); int k = (blk >> 5) & 3; int b = blk >> 7;
  bool rev = k >= 2, odd = k & 1;
  int d = tid;
  const u16* src = (odd ? xcTLD : xcLD) + (long)b*Ln*Di;
  const u16* dlg = dtsg + (long)(b*Kn + k)*Ln*6;
  const u32* bcg = BCg + (long)(b*Kn + k)*Ln*16;
  u16* yb = ys + (long)(b*Kn + k)*Ln*Di;
  float w[6], a[16], h[16];
  #pragma unroll
  for (int r = 0; r < 6; ++r) w[r] = ldv(dtw, ((long)k*Di + d)*6 + r);
  float bias = ldv(dtb, k*Di + d);
  long ci = (long)(b*Kn + k)*Gc + g;
  #pragma unroll
  for (int n = 0; n < 16; ++n){
    a[n] = -__expf(ldv(Alog, (long)d*16 + n));
    h[n] = Hin[ci*3072 + (long)d*16 + n];
  }
  for (int t = 0; t < CH/64; ++t){
    int l0 = g*CH + t*64;
    __syncthreads();
    for (int i = tid; i < 384; i += 192){ int j = i/6, c = i - 6*j; sdt[j*8 + c] = bfr(dlg[(long)l0*6 + i]); }
    for (int i = tid; i < 1024; i += 192){
      u32 v = bcg[(long)l0*16 + i];
      sB[i] = bfr((u16)(v & 0xffff));
      sC[i] = bfr((u16)(v >> 16));
    }
    for (int i = tid; i < 64*192; i += 192){
      int j = i / 192, dd = i % 192;
      int l = l0 + j; int pos = rev ? (Ln-1-l) : l;
      su[i] = src[(long)pos*Di + dd];
    }
    __syncthreads();
    if (fastA){
      for (int j = 0; j < 64; ++j){
        float xv = bias;
        #pragma unroll
        for (int r = 0; r < 6; ++r) xv += w[r]*sdt[j*8 + r];
        float dl, rr; sp_decay(xv, dl, rr);
        float du = dl * bfr(su[j*192 + d]);
        float Bv[16], Cv[16];
        *(float4*)&Bv[0]  = *(const float4*)&sB[j*16];
        *(float4*)&Bv[4]  = *(const float4*)&sB[j*16+4];
        *(float4*)&Bv[8]  = *(const float4*)&sB[j*16+8];
        *(float4*)&Bv[12] = *(const float4*)&sB[j*16+12];
        *(float4*)&Cv[0]  = *(const float4*)&sC[j*16];
        *(float4*)&Cv[4]  = *(const float4*)&sC[j*16+4];
        *(float4*)&Cv[8]  = *(const float4*)&sC[j*16+8];
        *(float4*)&Cv[12] = *(const float4*)&sC[j*16+12];
        float y = 0.f;
        float p = rr;
        #pragma unroll
        for (int n = 0; n < 16; ++n){
          h[n] = p*h[n] + du*Bv[n];
          y += h[n]*Cv[n];
          p *= rr;
        }
        int l = l0 + j; int le = rev ? (Ln-1-l) : l;
        int sp = odd ? ((le & 63)*64 + (le >> 6)) : le;
        yb[(long)sp*Di + d] = fbr(y);
      }
    } else {
      for (int j = 0; j < 64; ++j){
        float dl = bias;
        #pragma unroll
        for (int r = 0; r < 6; ++r) dl += w[r]*sdt[j*8 + r];
        dl = splus(dl);
        float du = dl * bfr(su[j*192 + d]);
        float Bv[16], Cv[16];
        *(float4*)&Bv[0]  = *(const float4*)&sB[j*16];
        *(float4*)&Bv[4]  = *(const float4*)&sB[j*16+4];
        *(float4*)&Bv[8]  = *(const float4*)&sB[j*16+8];
        *(float4*)&Bv[12] = *(const float4*)&sB[j*16+12];
        *(float4*)&Cv[0]  = *(const float4*)&sC[j*16];
        *(float4*)&Cv[4]  = *(const float4*)&sC[j*16+4];
        *(float4*)&Cv[8]  = *(const float4*)&sC[j*16+8];
        *(float4*)&Cv[12] = *(const float4*)&sC[j*16+12];
        float y = 0.f;
        #pragma unroll
        for (int n = 0; n < 16; ++n){
          h[n] = __expf(dl*a[n])*h[n] + du*Bv[n];
          y += h[n]*Cv[n];
        }
        int l = l0 + j; int le = rev ? (Ln-1-l) : l;
        int sp = odd ? ((le & 63)*64 + (le >> 6)) : le;
        yb[(long)sp*Di + d] = fbr(y);
      }
    }
  }
}
__global__ __launch_bounds__(192,3) void k_scan2(const u16* xcLD, const u16* xcTLD, const u16* dtsg,
                                                 const u32* BCg, const void* Alog, const void* dtw,
                                                 const void* dtb, const float* Hin, u16* ys,
                                                 const int* flag, const int* flag2){
  __shared__ float sdt[64*8];
  __shared__ float sB[64*16];
  __shared__ float sC[64*16];
  __shared__ u16 su[64*192];
  int f2 = *flag2;
  if (*flag) scan2_body<float>(xcLD, xcTLD, dtsg, BCg, (const float*)Alog, (const float*)dtw,
                               (const float*)dtb, Hin, ys, sdt, sB, sC, su, f2);
  else       scan2_body<bf16 >(xcLD, xcTLD, dtsg, BCg, (const bf16* )Alog, (const bf16* )dtw,
                               (const bf16* )dtb, Hin, ys, sdt, sB, sC, su, f2);
}

// ------- merge + skip + LayerNorm + gate + out_proj (wo staged in LDS bf16)
template<typename T>
__device__ void out_body(const u16* ys, const u16* xcLD, const u16* Z, const T* Dsv,
                         const T* lnw, const T* lnb, const T* wo, T* out, long obase,
                         u16* ty, u16* swo, float* sDs){
  int b = blockIdx.x >> 6, h = blockIdx.x & 63;
  int tid = threadIdx.x;
  const u16* xcb = xcLD + (long)b*Ln*Di;
  const u16* Zb = Z + (long)b*Ln*Di;
  const u16* pl0 = ys + (long)(b*Kn + 0)*Ln*Di;
  const u16* pl1 = ys + (long)(b*Kn + 1)*Ln*Di;
  const u16* pl2 = ys + (long)(b*Kn + 2)*Ln*Di;
  const u16* pl3 = ys + (long)(b*Kn + 3)*Ln*Di;
  if (tid < Di)
    sDs[tid] = ldv(Dsv, tid) + ldv(Dsv, Di+tid) + ldv(Dsv, 2*Di+tid) + ldv(Dsv, 3*Di+tid);
  __syncthreads();
  for (int i = tid; i < 96*192; i += 256){
    int r = i / 192, c = i % 192;
    swo[r*196 + c] = fbr(ldv(wo, i));
  }
  for (int i = tid; i < Di*64; i += 256){
    int j = i / 192, d = i % 192;
    long ls = (long)(h*64 + j)*Di + d;
    long lt = (long)(j*64 + h)*Di + d;
    float v = bfr(pl0[ls]) + bfr(pl2[ls]) + bfr(pl1[lt]) + bfr(pl3[lt])
            + sDs[d]*bfr(xcb[ls]);
    ty[j*196 + d] = fbr(v);
  }
  __syncthreads();
  int jj = tid >> 2, part = tid & 3;
  float s = 0.f, s2 = 0.f;
  for (int cix = part*48; cix < part*48 + 48; ++cix){
    float v = bfr(ty[jj*196 + cix]); s += v; s2 += v*v;
  }
  s += __shfl_xor(s, 1); s2 += __shfl_xor(s2, 1);
  s += __shfl_xor(s, 2); s2 += __shfl_xor(s2, 2);
  float mu = s * (1.f/192.f);
  float var = s2 * (1.f/192.f) - mu*mu;
  float rstd = rsqrtf(fmaxf(var, 0.f) + 1e-5f);
  long zbase = ((long)h*64 + jj)*Di;
  for (int cix = part*48; cix < part*48 + 48; ++cix){
    float zv = bfr(Zb[zbase + cix]);
    float g = zv / (1.f + __expf(-zv));
    float yn = (bfr(ty[jj*196 + cix]) - mu) * rstd * ldv(lnw, cix) + ldv(lnb, cix);
    ty[jj*196 + cix] = fbr(yn * g);
  }
  __syncthreads();
  int p = tid >> 2, q = tid & 3;
  float acc[24];
  #pragma unroll
  for (int oi = 0; oi < 24; ++oi) acc[oi] = 0.f;
  for (int kt = 0; kt < 6; ++kt){
    float xv[32];
    const u16* yr = &ty[p*196 + kt*32];
    #pragma unroll
    for (int j = 0; j < 32; j += 4){
      ushort4 u = *(const ushort4*)(yr + j);
      xv[j]=bfr(u.x); xv[j+1]=bfr(u.y); xv[j+2]=bfr(u.z); xv[j+3]=bfr(u.w);
    }
    #pragma unroll
    for (int oi = 0; oi < 24; ++oi){
      const u16* wr = &swo[(q*24 + oi)*196 + kt*32];
      float a2 = 0.f;
      #pragma unroll
      for (int j = 0; j < 32; j += 4){
        ushort4 wu = *(const ushort4*)(wr + j);
        a2 += bfr(wu.x)*xv[j] + bfr(wu.y)*xv[j+1] + bfr(wu.z)*xv[j+2] + bfr(wu.w)*xv[j+3];
      }
      acc[oi] += a2;
    }
  }
  long ob = obase + ((long)b*Ln + h*64 + p)*Cm + q*24;
  #pragma unroll
  for (int oi = 0; oi < 24; ++oi) stv(out, ob + oi, acc[oi]);
}
__global__ __launch_bounds__(256) void k_out(const u16* ys, const u16* xcLD, const u16* Z,
                                             const void* Dsv, const void* lnw, const void* lnb,
                                             const void* wo, void* out, long obase, const int* flag){
  __shared__ u16 ty[64*196];
  __shared__ u16 swo[96*196];
  __shared__ float sDs[Di];
  if (*flag) out_body<float>(ys, xcLD, Z, (const float*)Dsv, (const float*)lnw, (const float*)lnb,
                             (const float*)wo, (float*)out, obase, ty, swo, sDs);
  else       out_body<bf16 >(ys, xcLD, Z, (const bf16* )Dsv, (const bf16* )lnw, (const bf16* )lnb,
                             (const bf16* )wo, (bf16* )out, obase, ty, swo, sDs);
}

extern "C" void kernel_launch(void* const* d_in, const int* in_sizes, int n_in,
                              void* d_out, int out_size, void* d_ws, size_t ws_size,
                              hipStream_t stream){
  const void* x    = d_in[0];
  const void* ipw  = d_in[1];
  const void* cw   = d_in[2];
  const void* cb   = d_in[3];
  const void* xpw  = d_in[4];
  const void* dtw  = d_in[5];
  const void* dtb  = d_in[6];
  const void* Alog = d_in[7];
  const void* Dsv  = d_in[8];
  const void* lnw  = d_in[9];
  const void* lnb  = d_in[10];
  const void* wo   = d_in[11];

  const size_t PLANE = (size_t)Ln*Di*2;
  const size_t YSB   = (size_t)Kn*Ln*Di*2;
  const size_t SBB   = (size_t)Kn*Gc*Di*4;
  const size_t QBB   = (size_t)Kn*Gc*Di*Ns*4;
  const size_t HIB   = QBB;
  const size_t perB  = 4*PLANE + YSB + SBB + QBB + HIB;
  int Bc = 1;
  for (int c : {8, 4, 2, 1}) if (256 + (size_t)c*perB <= ws_size){ Bc = c; break; }
  int nch = 8 / Bc;

  char* base = (char*)d_ws;
  int*  flag  = (int*)base;
  int*  flag2 = (int*)(base + 8);
  u16* Z     = (u16*)(base + 256);
  u16* xcLD  = Z     + (size_t)Bc*Ln*Di;
  u16* xcTLD = xcLD  + (size_t)Bc*Ln*Di;
  u16* Xb    = xcTLD + (size_t)Bc*Ln*Di;
  u16* ys    = Xb    + (size_t)Bc*Ln*Di;
  float* Sb  = (float*)(ys + (size_t)Bc*Kn*Ln*Di);
  float* Qb  = Sb + (size_t)Bc*Kn*Gc*Di;
  float* Hin = Qb + (size_t)Bc*Kn*Gc*Di*Ns;
  u16* dts   = Xb;
  u32* BC    = (u32*)(dts + (size_t)Bc*Kn*Ln*6);

  k_detect<<<1, 256, 0, stream>>>((const u16*)x, Alog, flag, flag2);

  for (int ch = 0; ch < nch; ++ch){
    long xoff = (long)ch*Bc*Ln*Cm;
    k_inproj <<<Bc*Ln/64,   256, 0, stream>>>(x, xoff, ipw, Xb, Z, flag);
    k_conv   <<<Bc*Hn,      256, 0, stream>>>(Xb, cw, cb, xcLD, xcTLD, flag);
    k_proj   <<<Bc*(Ln/64)*2, 256, 0, stream>>>(xcLD, xcTLD, xpw, dts, BC, flag);
    k_scan1  <<<Bc*Kn*Gc,   192, 0, stream>>>(xcLD, xcTLD, dts, BC, Alog, dtw, dtb, Sb, Qb, flag, flag2);
    k_fix    <<<Bc*Kn,      256, 0, stream>>>(Sb, Qb, Alog, Hin, flag);
    k_scan2  <<<Bc*Kn*Gc,   192, 0, stream>>>(xcLD, xcTLD, dts, BC, Alog, dtw, dtb, Hin, ys, flag, flag2);
    k_out    <<<Bc*Hn,      256, 0, stream>>>(ys, xcLD, Z, Dsv, lnw, lnb, wo, d_out, xoff, flag);
  }
}